// Round 8
// baseline (286.241 us; speedup 1.0000x reference)
//
#include <hip/hip_runtime.h>
#include <hip/hip_bf16.h>
#include <hip/hip_fp16.h>

// DiscoMixerBlock: B=1, H=90, W=180 (P=16200), MODEL_DIM=130 (L=128),
// NH=8, HD=16, S=16, K=25, NNB=25, MH=32, FH=256. All fp32.
#define P_TOT 16200
#define MODEL_DIMC 130
#define L_DIM 128
#define NHH 8
#define S_DIM 16
#define K_DIM 25
#define NNBC 25
#define MH_DIM 32
#define FH_DIM 256

// exact gelu: x * 0.5 * (1 + erf(x/sqrt(2))); erf via Abramowitz-Stegun 7.1.26 (|err|<=1.5e-7)
__device__ __forceinline__ float gelu_f(float x) {
    float z = fabsf(x) * 0.70710678118654752440f;
    float t = __builtin_amdgcn_rcpf(fmaf(0.3275911f, z, 1.0f));
    float poly = t * fmaf(t, fmaf(t, fmaf(t, fmaf(t, 1.061405429f, -1.453152027f),
                                          1.421413741f), -0.284496736f), 0.254829592f);
    float e = __expf(-z * z);
    float erfp = fmaf(-poly, e, 1.0f);     // erf(|x|/sqrt2), >=0
    float erfv = copysignf(erfp, x);
    return 0.5f * x * (1.0f + erfv);
}

// ---------------- K1: three block ranges ----------------
// [0,NB1): bw[p][n][s] = sum_k disco_w[s][k]*basis[k][p][n], dense stores via LDS transpose
// [NB1,NB1+NPACK): pack x_learn -> fp16 xh[P][128]
// [NB1+NPACK,...): transpose head_w1 [h][s][m] -> w1t [h][m][s]
#define NB1 1583                 // ceil(405000/256)
#define NPACK 1013               // ceil(16200/16)
__global__ __launch_bounds__(256) void k1_bw_pack(
        const float* __restrict__ basis, const float* __restrict__ disco_w,
        const float* __restrict__ x, const float* __restrict__ hw1,
        float* __restrict__ bw, __half* __restrict__ xh, float* __restrict__ w1t) {
    int bid = blockIdx.x;
    int tid = threadIdx.x;
    if (bid >= NB1 + NPACK) {            // w1t transpose (block-uniform branch)
        int i = (bid - NB1 - NPACK) * 256 + tid;
        if (i < NHH * S_DIM * MH_DIM) {
            int h = i >> 9, s = (i >> 5) & 15, m = i & 31;
            w1t[h * 512 + m * 16 + s] = hw1[i];
        }
        return;
    }
    if (bid >= NB1) {                    // fp16 pack: 16 rows per block
        int p0 = (bid - NB1) * 16;
        for (int j = tid; j < 16 * 128; j += 256) {
            int pl = j >> 7, c = j & 127;
            int p = p0 + pl;
            if (p < P_TOT) xh[(size_t)p * 128 + c] = __float2half(x[(size_t)p * MODEL_DIMC + c]);
        }
        return;
    }
    // main: bw compute
    __shared__ float wT[K_DIM * 16];                 // [k][s]
    __shared__ __align__(16) float st[4][64][17];    // store-transpose tile
    for (int i = tid; i < S_DIM * K_DIM; i += 256) { // FIX(R7): strided loop, 400 > 256 threads
        int s = i / 25, k = i % 25;
        wT[k * 16 + s] = disco_w[i];
    }
    __syncthreads();
    int i = bid * 256 + tid;             // flat (p,n)
    int ii = min(i, P_TOT * NNBC - 1);
    float bv[K_DIM];
#pragma unroll
    for (int k = 0; k < K_DIM; k++) bv[k] = basis[k * (P_TOT * NNBC) + ii];
    float acc[S_DIM];
#pragma unroll
    for (int s = 0; s < S_DIM; s++) acc[s] = 0.f;
    const float4* wT4 = (const float4*)wT;
#pragma unroll
    for (int k = 0; k < K_DIM; k++) {
        float b = bv[k];
        float4 w0 = wT4[k * 4 + 0], w1 = wT4[k * 4 + 1];
        float4 w2 = wT4[k * 4 + 2], w3 = wT4[k * 4 + 3];
        acc[0]  = fmaf(b, w0.x, acc[0]);  acc[1]  = fmaf(b, w0.y, acc[1]);
        acc[2]  = fmaf(b, w0.z, acc[2]);  acc[3]  = fmaf(b, w0.w, acc[3]);
        acc[4]  = fmaf(b, w1.x, acc[4]);  acc[5]  = fmaf(b, w1.y, acc[5]);
        acc[6]  = fmaf(b, w1.z, acc[6]);  acc[7]  = fmaf(b, w1.w, acc[7]);
        acc[8]  = fmaf(b, w2.x, acc[8]);  acc[9]  = fmaf(b, w2.y, acc[9]);
        acc[10] = fmaf(b, w2.z, acc[10]); acc[11] = fmaf(b, w2.w, acc[11]);
        acc[12] = fmaf(b, w3.x, acc[12]); acc[13] = fmaf(b, w3.y, acc[13]);
        acc[14] = fmaf(b, w3.z, acc[14]); acc[15] = fmaf(b, w3.w, acc[15]);
    }
    // dense stores: stage through LDS so consecutive lanes write consecutive float4s
    int wv = tid >> 6, ln = tid & 63;
#pragma unroll
    for (int s = 0; s < 16; s++) st[wv][ln][s] = acc[s];
    __builtin_amdgcn_s_waitcnt(0);       // full wait incl. lgkmcnt(0): wave-local LDS ordering
    float4* outp4 = (float4*)bw;
    size_t base4 = ((size_t)bid * 256 + wv * 64) * 4;
    size_t lim4 = (size_t)P_TOT * NNBC * 4;
#pragma unroll
    for (int q = 0; q < 4; q++) {
        int g = ln + 64 * q;
        float4 v = *(const float4*)&st[wv][g >> 2][(g & 3) * 4];
        if (base4 + g < lim4) outp4[base4 + g] = v;
    }
}

// ---------------- K2: fused disco gather-dot + head MLP + residual -> xmix[p][c] ----------------
// Block = 4 waves = 4 points. Phase 1: wave = point, lane owns channels {2*lane, 2*lane+1}
// gathered from fp16 xh (4.15MB, ~L2-resident; ONE dword load per neighbor per lane),
// depth-5 software pipeline; nbr/bw via wave-uniform s_load.
// LDS y-tile 32768B; rotation swizzle col=(c+8*pt)&127 keeps write+read at <=2 lanes/bank.
__global__ __launch_bounds__(256, 5) void k2_disco_head(
        const float* __restrict__ x, const __half* __restrict__ xh,
        const int* __restrict__ nbr,
        const float* __restrict__ bw, const float* __restrict__ w1t,
        const float* __restrict__ head_b1, const float* __restrict__ head_w2,
        const float* __restrict__ head_b2, const float* __restrict__ disco_b,
        float* __restrict__ xmix) {
    __shared__ float ylds[4 * 2048];     // [pt][s][colrot]

    int tid  = threadIdx.x;
    int lane = tid & 63;
    int wv   = __builtin_amdgcn_readfirstlane(tid >> 6);   // uniform wave id 0..3
    int p0   = blockIdx.x * 4;
    int p    = p0 + wv;                                    // uniform point

    const float* bwp = bw + (size_t)p * (NNBC * S_DIM);    // uniform base
    const int*   nbp = nbr + p * NNBC;                     // uniform base

    int un[NNBC];                                          // uniform -> SGPRs
#pragma unroll
    for (int j = 0; j < NNBC; j++) un[j] = nbp[j];

    float y0[16], y1[16];
#pragma unroll
    for (int s = 0; s < 16; s++) { float db = disco_b[s]; y0[s] = db; y1[s] = db; }

    const uint* xbase = (const uint*)xh + lane;            // element {2*lane,2*lane+1}

    uint cur[5], nxt[5];
#pragma unroll
    for (int j = 0; j < 5; j++) cur[j] = xbase[(size_t)un[j] * 64];

#pragma unroll
    for (int g = 0; g < 5; g++) {
        if (g < 4) {
#pragma unroll
            for (int j = 0; j < 5; j++) nxt[j] = xbase[(size_t)un[(g + 1) * 5 + j] * 64];
        }
#pragma unroll
        for (int j = 0; j < 5; j++) {
            int nb = g * 5 + j;
            __half2 h2 = *reinterpret_cast<const __half2*>(&cur[j]);
            float ga = __low2float(h2);
            float gb = __high2float(h2);
#pragma unroll
            for (int s = 0; s < 16; s++) {
                float w = bwp[nb * 16 + s];                // uniform -> SGPR
                y0[s] = fmaf(ga, w, y0[s]);
                y1[s] = fmaf(gb, w, y1[s]);
            }
        }
        if (g < 4) {
#pragma unroll
            for (int j = 0; j < 5; j++) cur[j] = nxt[j];
        }
    }

    // Phase 2: y -> LDS, rotated columns; float2 per lane (cols 2l+8wv, +1; no wrap: even start)
    {
        int cr = (2 * lane + 8 * wv) & 127;
#pragma unroll
        for (int s = 0; s < 16; s++) {
            float2 v; v.x = y0[s]; v.y = y1[s];
            *(float2*)&ylds[wv * 2048 + s * 128 + cr] = v;
        }
    }
    __syncthreads();

    // Phase 3: wave handles heads {wv, wv+4}; lane -> (ptl = lane>>4, d = lane&15)
    int ptl = lane >> 4;
    int d   = lane & 15;
    int ybase = ptl * 2048;
    int rot   = 8 * ptl;
#pragma unroll
    for (int t = 0; t < 2; t++) {
        int hh = __builtin_amdgcn_readfirstlane(wv + 4 * t);
        int cc  = hh * 16 + d;
        int col = (cc + rot) & 127;
        float yv[16];
#pragma unroll
        for (int s = 0; s < 16; s++)
            yv[s] = ylds[ybase + s * 128 + col];           // 2 lanes/bank: free
        const float* wrow = w1t + hh * (MH_DIM * S_DIM);   // uniform
        const float* b1r  = head_b1 + hh * MH_DIM;
        const float* w2r  = head_w2 + hh * MH_DIM;
        float acc = head_b2[hh];
#pragma unroll 1
        for (int m = 0; m < MH_DIM; m += 2) {
            const float* wm0 = wrow + m * 16;
            const float* wm1 = wrow + m * 16 + 16;
            float a0 = b1r[m], a1 = b1r[m + 1];
            float a0b = 0.f, a1b = 0.f;
#pragma unroll
            for (int s = 0; s < 8; s++) {
                a0  = fmaf(yv[s],     wm0[s],     a0);
                a0b = fmaf(yv[s + 8], wm0[s + 8], a0b);
                a1  = fmaf(yv[s],     wm1[s],     a1);
                a1b = fmaf(yv[s + 8], wm1[s + 8], a1b);
            }
            a0 += a0b; a1 += a1b;
            a0 = gelu_f(a0);
            a1 = gelu_f(a1);
            acc = fmaf(a0, w2r[m],     acc);
            acc = fmaf(a1, w2r[m + 1], acc);
        }
        int pp = p0 + ptl;
        xmix[pp * L_DIM + cc] = acc + x[(size_t)pp * MODEL_DIMC + cc];
    }
}

// ---------------- K3: fused FFN, TILE_P=32 (halved weight re-reads); hf in LDS ----------------
// Phase A: fid=tid&63 -> 4 f (full w1 row per wave, zero redundancy), wid=tid>>6 -> 8 pts.
// Phase B: lid=tid&31 -> 4 l, pgb=tid>>5 -> 4 pts.
__global__ __launch_bounds__(256, 3) void k3_ffn(
        const float* __restrict__ x, const float* __restrict__ xmix,
        const float* __restrict__ w1, const float* __restrict__ b1,
        const float* __restrict__ w2, const float* __restrict__ b2,
        float* __restrict__ out) {
    __shared__ __align__(16) float xm[32 * 132];    // 16.9 KB, padded stride 132
    __shared__ __align__(16) float hfl[32 * 260];   // 33.3 KB, padded stride 260
    int tid = threadIdx.x;
    int p0 = blockIdx.x * 32;
    int valid = min(32, P_TOT - p0);
    {
        const float4* src = (const float4*)(xmix + (size_t)p0 * L_DIM);
        for (int j = tid; j < valid * 32; j += 256) {
            float4 v = src[j];
            int pt = j >> 5, q = j & 31;
            *(float4*)&xm[pt * 132 + q * 4] = v;
        }
    }
    __syncthreads();

    // Phase A: hf = gelu(xm @ w1 + b1)
    {
        int fid = tid & 63, wid = tid >> 6;
        int f0 = fid * 4;
        float4 bb = *(const float4*)&b1[f0];
        float acc[8][4];                             // [pt][f]
#pragma unroll
        for (int i = 0; i < 8; i++) {
            acc[i][0] = bb.x; acc[i][1] = bb.y; acc[i][2] = bb.z; acc[i][3] = bb.w;
        }
#pragma unroll 2
        for (int k0 = 0; k0 < 128; k0 += 4) {
            float4 w4[4];
#pragma unroll
            for (int j = 0; j < 4; j++)
                w4[j] = *(const float4*)&w1[(k0 + j) * FH_DIM + f0];
#pragma unroll
            for (int i = 0; i < 8; i++) {
                float4 xv = *(const float4*)&xm[(wid * 8 + i) * 132 + k0];  // LDS broadcast
                acc[i][0] = fmaf(xv.x, w4[0].x, acc[i][0]);
                acc[i][1] = fmaf(xv.x, w4[0].y, acc[i][1]);
                acc[i][2] = fmaf(xv.x, w4[0].z, acc[i][2]);
                acc[i][3] = fmaf(xv.x, w4[0].w, acc[i][3]);
                acc[i][0] = fmaf(xv.y, w4[1].x, acc[i][0]);
                acc[i][1] = fmaf(xv.y, w4[1].y, acc[i][1]);
                acc[i][2] = fmaf(xv.y, w4[1].z, acc[i][2]);
                acc[i][3] = fmaf(xv.y, w4[1].w, acc[i][3]);
                acc[i][0] = fmaf(xv.z, w4[2].x, acc[i][0]);
                acc[i][1] = fmaf(xv.z, w4[2].y, acc[i][1]);
                acc[i][2] = fmaf(xv.z, w4[2].z, acc[i][2]);
                acc[i][3] = fmaf(xv.z, w4[2].w, acc[i][3]);
                acc[i][0] = fmaf(xv.w, w4[3].x, acc[i][0]);
                acc[i][1] = fmaf(xv.w, w4[3].y, acc[i][1]);
                acc[i][2] = fmaf(xv.w, w4[3].z, acc[i][2]);
                acc[i][3] = fmaf(xv.w, w4[3].w, acc[i][3]);
            }
        }
#pragma unroll
        for (int i = 0; i < 8; i++) {
            int pt = wid * 8 + i;
            float4 v;
            v.x = gelu_f(acc[i][0]);
            v.y = gelu_f(acc[i][1]);
            v.z = gelu_f(acc[i][2]);
            v.w = gelu_f(acc[i][3]);
            *(float4*)&hfl[pt * 260 + f0] = v;
        }
    }
    __syncthreads();

    // Phase B: out = hfl @ w2 + b2 + xm (+ sincos passthrough)
    {
        int lid = tid & 31, pgb = tid >> 5;
        int l0 = lid * 4;
        float4 bb = *(const float4*)&b2[l0];
        float acc[4][4];                             // [pt][l]
#pragma unroll
        for (int i = 0; i < 4; i++) {
            acc[i][0] = bb.x; acc[i][1] = bb.y; acc[i][2] = bb.z; acc[i][3] = bb.w;
        }
#pragma unroll 2
        for (int f0 = 0; f0 < FH_DIM; f0 += 4) {
            float4 w4[4];
#pragma unroll
            for (int j = 0; j < 4; j++)
                w4[j] = *(const float4*)&w2[(f0 + j) * L_DIM + l0];
#pragma unroll
            for (int i = 0; i < 4; i++) {
                float hv = hfl[(pgb * 4 + i) * 260 + f0];
                float hv1 = hfl[(pgb * 4 + i) * 260 + f0 + 1];
                float hv2 = hfl[(pgb * 4 + i) * 260 + f0 + 2];
                float hv3 = hfl[(pgb * 4 + i) * 260 + f0 + 3];
                acc[i][0] = fmaf(hv, w4[0].x, acc[i][0]);
                acc[i][1] = fmaf(hv, w4[0].y, acc[i][1]);
                acc[i][2] = fmaf(hv, w4[0].z, acc[i][2]);
                acc[i][3] = fmaf(hv, w4[0].w, acc[i][3]);
                acc[i][0] = fmaf(hv1, w4[1].x, acc[i][0]);
                acc[i][1] = fmaf(hv1, w4[1].y, acc[i][1]);
                acc[i][2] = fmaf(hv1, w4[1].z, acc[i][2]);
                acc[i][3] = fmaf(hv1, w4[1].w, acc[i][3]);
                acc[i][0] = fmaf(hv2, w4[2].x, acc[i][0]);
                acc[i][1] = fmaf(hv2, w4[2].y, acc[i][1]);
                acc[i][2] = fmaf(hv2, w4[2].z, acc[i][2]);
                acc[i][3] = fmaf(hv2, w4[2].w, acc[i][3]);
                acc[i][0] = fmaf(hv3, w4[3].x, acc[i][0]);
                acc[i][1] = fmaf(hv3, w4[3].y, acc[i][1]);
                acc[i][2] = fmaf(hv3, w4[3].z, acc[i][2]);
                acc[i][3] = fmaf(hv3, w4[3].w, acc[i][3]);
            }
        }
#pragma unroll
        for (int i = 0; i < 4; i++) {
            int pl = pgb * 4 + i;
            if (pl < valid) {
                int pp = p0 + pl;
                float4 xm4 = *(const float4*)&xm[pl * 132 + l0];
                float2 o01, o23;
                o01.x = acc[i][0] + xm4.x;
                o01.y = acc[i][1] + xm4.y;
                o23.x = acc[i][2] + xm4.z;
                o23.y = acc[i][3] + xm4.w;
                *(float2*)&out[(size_t)pp * MODEL_DIMC + l0]     = o01;
                *(float2*)&out[(size_t)pp * MODEL_DIMC + l0 + 2] = o23;
            }
        }
        if (tid < 64) {
            int pt = tid >> 1, wch = tid & 1;
            if (pt < valid) {
                int pp = p0 + pt;
                out[(size_t)pp * MODEL_DIMC + 128 + wch] = x[(size_t)pp * MODEL_DIMC + 128 + wch];
            }
        }
    }
}

extern "C" void kernel_launch(void* const* d_in, const int* in_sizes, int n_in,
                              void* d_out, int out_size, void* d_ws, size_t ws_size,
                              hipStream_t stream) {
    const float* x        = (const float*)d_in[0];
    const int*   nbr      = (const int*)  d_in[1];
    const float* basis    = (const float*)d_in[2];
    const float* disco_w  = (const float*)d_in[3];
    const float* disco_b  = (const float*)d_in[4];
    const float* head_w1  = (const float*)d_in[5];
    const float* head_b1  = (const float*)d_in[6];
    const float* head_w2  = (const float*)d_in[7];
    const float* head_b2  = (const float*)d_in[8];
    const float* ffn_w1   = (const float*)d_in[9];
    const float* ffn_b1   = (const float*)d_in[10];
    const float* ffn_w2   = (const float*)d_in[11];
    const float* ffn_b2   = (const float*)d_in[12];
    float* out = (float*)d_out;

    // ws layout: bw [P*400] (25.9MB) | xmix [P*128] (8.3MB) | w1t [4096] (16KB)
    float* bw   = (float*)d_ws;
    float* xmix = bw + (size_t)P_TOT * NNBC * S_DIM;
    float* w1t  = xmix + (size_t)P_TOT * L_DIM;
    // fp16 packed x_learn lives in d_out scratch (4.15MB < 8.4MB); dead before k3 writes out.
    __half* xh  = (__half*)d_out;

    hipLaunchKernelGGL(k1_bw_pack, dim3(NB1 + NPACK + 16), dim3(256), 0, stream,
                       basis, disco_w, x, head_w1, bw, xh, w1t);
    hipLaunchKernelGGL(k2_disco_head, dim3(P_TOT / 4), dim3(256), 0, stream,
                       x, xh, nbr, bw, w1t, head_b1, head_w2, head_b2, disco_b, xmix);
    hipLaunchKernelGGL(k3_ffn, dim3((P_TOT + 31) / 32), dim3(256), 0, stream,
                       x, xmix, ffn_w1, ffn_b1, ffn_w2, ffn_b2, out);
}